// Round 5
// baseline (251.551 us; speedup 1.0000x reference)
//
#include <hip/hip_runtime.h>
#include <math.h>

#define B_TOT   1024
#define S_DIM   64
#define N_DIM   256
#define UNFOLDS 12
#define EPSF    1e-8f
#define L2E     1.4426950408889634f

typedef float v2f __attribute__((ext_vector_type(2)));

// Guaranteed-native transcendentals.
#if defined(__has_builtin)
#  if __has_builtin(__builtin_amdgcn_exp2f)
#    define FEXP2(x) __builtin_amdgcn_exp2f(x)
#  endif
#  if __has_builtin(__builtin_amdgcn_rcpf)
#    define FRCP(x) __builtin_amdgcn_rcpf(x)
#  endif
#endif
#ifndef FEXP2
__device__ __forceinline__ float __fexp2_asm(float x){ float r; asm("v_exp_f32 %0, %1" : "=v"(r) : "v"(x)); return r; }
#  define FEXP2(x) __fexp2_asm(x)
#endif
#ifndef FRCP
__device__ __forceinline__ float __frcp_asm(float x){ float r; asm("v_rcp_f32 %0, %1" : "=v"(r) : "v"(x)); return r; }
#  define FRCP(x) __frcp_asm(x)
#endif

__device__ __forceinline__ float softplus_f(float x) {
    return log1pf(expf(x));
}

// ---- rcp-free sigmoid pair ----
// r = 1/(1+2^t).  u = 2^(-|t|) in (0,1];  p ~= 1/(1+u) via deg-3 minimax
// (err ~1.2e-3) + 1 Newton step (err ~6e-6);  r = p * (t>0 ? u : 1)
// (exact: u/(1+u) = 1 - 1/(1+u)).  Saturation exact at u=0.
#define C0f  0.99852065f
#define C1f (-0.94689302f)
#define C2f  0.67589024f
#define C3f (-0.22856384f)

__device__ __forceinline__ v2f sig2(v2f t) {
    float u0 = FEXP2(-__builtin_fabsf(t.x));   // folds to v_exp_f32 with -|.| modifiers
    float u1 = FEXP2(-__builtin_fabsf(t.y));
    v2f u; u.x = u0; u.y = u1;
    v2f p = ((C3f * u + C2f) * u + C1f) * u + C0f;   // pk-fma Horner
    p = p * (2.0f - (u + 1.0f) * p);                 // Newton refine
    v2f m;
    m.x = t.x > 0.0f ? u.x : 1.0f;
    m.y = t.y > 0.0f ? u.y : 1.0f;
    return p * m;
}

// Pack per-(pre,post) params as float4 {A, B, WE, WEr}, i-major / j-contiguous:
//   sigmoid(sigma*(v-mu)) = 1/(1+exp2(A*v+B)), A=-L2E*sigma, B=L2E*sigma*mu
//   WE = softplus(w)*mask, WEr = WE*erev
__global__ void ltc_precompute(const float* __restrict__ gleak, const float* __restrict__ vleak,
                               const float* __restrict__ cm,    const float* __restrict__ w,
                               const float* __restrict__ sigma, const float* __restrict__ mu,
                               const float* __restrict__ erev,
                               const float* __restrict__ sw,    const float* __restrict__ ssig,
                               const float* __restrict__ smu,   const float* __restrict__ serev,
                               const float* __restrict__ mask,  const float* __restrict__ smask,
                               float4* __restrict__ p4, float4* __restrict__ s4,
                               float4* __restrict__ pj)
{
    const int idx = blockIdx.x * blockDim.x + threadIdx.x;
    if (idx < N_DIM * N_DIM) {
        float we = softplus_f(w[idx]) * mask[idx];
        float sg = sigma[idx];
        float4 o;
        o.x = -L2E * sg;
        o.y =  L2E * sg * mu[idx];
        o.z =  we;
        o.w =  we * erev[idx];
        p4[idx] = o;
    }
    if (idx < S_DIM * N_DIM) {
        float we = softplus_f(sw[idx]) * smask[idx];
        float sg = ssig[idx];
        float4 o;
        o.x = -L2E * sg;
        o.y =  L2E * sg * smu[idx];
        o.z =  we;
        o.w =  we * serev[idx];
        s4[idx] = o;
    }
    if (idx < N_DIM) {
        float g = softplus_f(gleak[idx]);
        float4 o;
        o.x = softplus_f(cm[idx]) * (float)UNFOLDS;  // cm_t
        o.y = g;
        o.z = g * vleak[idx];
        o.w = 0.0f;
        pj[idx] = o;
    }
}

// 1024 threads/block, 256 blocks, 4 batches each. j = tid&255, q = tid>>8
// (0..3), q covers i in [64q, 64q+64). Redundant combine in all q-groups.
// All locals named scalars/float2/float4 — no indexed arrays (scratch-spill).
__global__ __launch_bounds__(1024, 2)
void ltc_main(const float* __restrict__ inputs, const float* __restrict__ state,
              const float4* __restrict__ p4, const float4* __restrict__ s4,
              const float4* __restrict__ pj, float* __restrict__ out)
{
    __shared__ float4 v4[N_DIM];        // v[i], component = batch
    __shared__ float4 pnum[4][N_DIM];   // partials [q][j]
    __shared__ float4 pden[4][N_DIM];
    __shared__ float  in_lds[4][S_DIM];

    const int tid = threadIdx.x;
    const int j   = tid & (N_DIM - 1);
    const int q   = tid >> 8;
    const int b0  = blockIdx.x << 2;

    ((float*)v4)[(j << 2) + q] = state[(b0 + q) * N_DIM + j];
    if (tid < 4 * S_DIM) in_lds[tid >> 6][tid & 63] = inputs[b0 * S_DIM + tid];

    const float4 c = pj[j];
    const float cmt = c.x, gl = c.y, glv = c.z;
    const float cg  = cmt + gl + EPSF;
    __syncthreads();

    // ---- sensory pass: q covers s in [16q, 16q+16) ----
    v2f anA = {0.f, 0.f}, adA = {0.f, 0.f};
    v2f anB = {0.f, 0.f}, adB = {0.f, 0.f};
    {
        const float4* __restrict__ sr = s4 + (q << 4) * N_DIM + j;
        const int sbase = q << 4;
        #pragma unroll 4
        for (int s = 0; s < 16; ++s) {
            const float4 p = sr[s * N_DIM];
            v2f tA, tB;
            tA.x = fmaf(p.x, in_lds[0][sbase + s], p.y);
            tA.y = fmaf(p.x, in_lds[1][sbase + s], p.y);
            tB.x = fmaf(p.x, in_lds[2][sbase + s], p.y);
            tB.y = fmaf(p.x, in_lds[3][sbase + s], p.y);
            v2f rA = sig2(tA), rB = sig2(tB);
            anA += rA * p.w; adA += rA * p.z;
            anB += rB * p.w; adB += rB * p.z;
        }
    }
    pnum[q][j] = make_float4(anA.x, anA.y, anB.x, anB.y);
    pden[q][j] = make_float4(adA.x, adA.y, adB.x, adB.y);
    __syncthreads();

    // all threads redundantly reduce sensory partials into registers
    float4 sn = make_float4(0.f, 0.f, 0.f, 0.f);
    float4 sd = make_float4(0.f, 0.f, 0.f, 0.f);
    #pragma unroll
    for (int qq = 0; qq < 4; ++qq) {
        const float4 a = pnum[qq][j], b = pden[qq][j];
        sn.x += a.x; sn.y += a.y; sn.z += a.z; sn.w += a.w;
        sd.x += b.x; sd.y += b.y; sd.z += b.z; sd.w += b.w;
    }
    __syncthreads();   // pnum/pden reused below

    // ---- 12 ODE unfolds ----
    const float4* __restrict__ pr = p4 + (q << 6) * N_DIM + j;
    const float4* __restrict__ vr = v4 + (q << 6);

    #pragma unroll 1
    for (int step = 0; step < UNFOLDS; ++step) {
        v2f nA = {0.f, 0.f}, dA = {0.f, 0.f};
        v2f nB = {0.f, 0.f}, dB = {0.f, 0.f};

        #pragma unroll 8
        for (int i = 0; i < 64; ++i) {
            const float4 p  = pr[i * N_DIM];   // coalesced dwordx4, L2-resident
            const float4 vv = vr[i];           // LDS broadcast
            v2f tA, tB;
            tA.x = fmaf(p.x, vv.x, p.y);
            tA.y = fmaf(p.x, vv.y, p.y);
            tB.x = fmaf(p.x, vv.z, p.y);
            tB.y = fmaf(p.x, vv.w, p.y);
            v2f rA = sig2(tA), rB = sig2(tB);
            nA += rA * p.w; dA += rA * p.z;
            nB += rB * p.w; dB += rB * p.z;
        }

        const float4 vo = v4[j];   // read old v BEFORE the barrier
        pnum[q][j] = make_float4(nA.x, nA.y, nB.x, nB.y);
        pden[q][j] = make_float4(dA.x, dA.y, dB.x, dB.y);
        __syncthreads();

        // redundant combine in all q-groups (bitwise-identical results)
        float4 tn = sn, td = sd;
        #pragma unroll
        for (int qq = 0; qq < 4; ++qq) {
            const float4 a = pnum[qq][j], b = pden[qq][j];
            tn.x += a.x; tn.y += a.y; tn.z += a.z; tn.w += a.w;
            td.x += b.x; td.y += b.y; td.z += b.z; td.w += b.w;
        }
        float4 vn;
        vn.x = (fmaf(cmt, vo.x, glv) + tn.x) * FRCP(cg + td.x);
        vn.y = (fmaf(cmt, vo.y, glv) + tn.y) * FRCP(cg + td.y);
        vn.z = (fmaf(cmt, vo.z, glv) + tn.z) * FRCP(cg + td.z);
        vn.w = (fmaf(cmt, vo.w, glv) + tn.w) * FRCP(cg + td.w);
        v4[j] = vn;                // 4 writers, identical bits — benign
        __syncthreads();
    }

    out[(b0 + q) * N_DIM + j] = ((const float*)v4)[(j << 2) + q];
}

extern "C" void kernel_launch(void* const* d_in, const int* in_sizes, int n_in,
                              void* d_out, int out_size, void* d_ws, size_t ws_size,
                              hipStream_t stream)
{
    const float* inputs = (const float*)d_in[0];
    const float* state  = (const float*)d_in[1];
    const float* gleak  = (const float*)d_in[2];
    const float* vleak  = (const float*)d_in[3];
    const float* cm     = (const float*)d_in[4];
    const float* w      = (const float*)d_in[5];
    const float* sigma  = (const float*)d_in[6];
    const float* mu     = (const float*)d_in[7];
    const float* erev   = (const float*)d_in[8];
    const float* sw     = (const float*)d_in[9];
    const float* ssig   = (const float*)d_in[10];
    const float* smu    = (const float*)d_in[11];
    const float* serev  = (const float*)d_in[12];
    const float* mask   = (const float*)d_in[13];
    const float* smask  = (const float*)d_in[14];

    float4* p4 = (float4*)d_ws;                 // [N*N] = 1 MiB
    float4* s4 = p4 + N_DIM * N_DIM;            // [S*N] = 256 KiB
    float4* pj = s4 + S_DIM * N_DIM;            // [N]   = 4 KiB

    ltc_precompute<<<(N_DIM * N_DIM + 255) / 256, 256, 0, stream>>>(
        gleak, vleak, cm, w, sigma, mu, erev, sw, ssig, smu, serev, mask, smask,
        p4, s4, pj);

    ltc_main<<<B_TOT / 4, 1024, 0, stream>>>(inputs, state, p4, s4, pj, (float*)d_out);
}